// Round 1
// baseline (621.691 us; speedup 1.0000x reference)
//
#include <hip/hip_runtime.h>
#include <hip/hip_bf16.h>
#include <stdint.h>

typedef unsigned short u16;
typedef __bf16 bf16x8 __attribute__((ext_vector_type(8)));
typedef float f32x4 __attribute__((ext_vector_type(4)));

#define NROW 16384   // b*h*w
#define CCH  512
#define KCB  4096
#define INVT 14.2857142857142857f  // 1/0.07

__device__ __forceinline__ u16 f2b(float f) {
  __hip_bfloat16 h = __float2bfloat16(f);
  return __builtin_bit_cast(u16, h);
}
__device__ __forceinline__ float b2f(u16 u) {
  union { uint32_t i; float f; } z; z.i = ((uint32_t)u) << 16; return z.f;
}
// async global->LDS, 16B per lane; LDS dest must be wave-uniform base + lane*16
__device__ __forceinline__ void g2l16(const void* g, void* l) {
  __builtin_amdgcn_global_load_lds(
      (__attribute__((address_space(1))) void*)(uintptr_t)g,
      (__attribute__((address_space(3))) void*)(uint32_t)(uintptr_t)l, 16, 0, 0);
}

// ---------------- prep: feat (b,c,hw) -> Xhi/Xlo bf16 (n, c), n = b*1024+hw ----
__global__ __launch_bounds__(256) void prep_x(const float* __restrict__ feat,
                                              u16* __restrict__ Xhi, u16* __restrict__ Xlo) {
  __shared__ float sm[64][65];
  int b = blockIdx.x >> 4;
  int hw0 = (blockIdx.x & 15) << 6;
  int t = threadIdx.x;
  int hwi = t & 63, ci0 = t >> 6;
  for (int c0 = 0; c0 < 512; c0 += 64) {
    for (int ci = ci0; ci < 64; ci += 4)
      sm[ci][hwi] = feat[((b * 512 + c0 + ci) << 10) + hw0 + hwi];
    __syncthreads();
    int cj = t & 7;
    for (int w = 0; w < 2; ++w) {
      int hj = (t >> 3) + (w << 5);
      int n = (b << 10) + hw0 + hj;
      uint32_t hp[4], lp[4];
      for (int p = 0; p < 4; ++p) {
        float v0 = sm[cj * 8 + p * 2 + 0][hj];
        float v1 = sm[cj * 8 + p * 2 + 1][hj];
        u16 h0 = f2b(v0), h1 = f2b(v1);
        u16 l0 = f2b(v0 - b2f(h0)), l1 = f2b(v1 - b2f(h1));
        hp[p] = (uint32_t)h0 | ((uint32_t)h1 << 16);
        lp[p] = (uint32_t)l0 | ((uint32_t)l1 << 16);
      }
      *(uint4*)(Xhi + n * 512 + c0 + cj * 8) = make_uint4(hp[0], hp[1], hp[2], hp[3]);
      *(uint4*)(Xlo + n * 512 + c0 + cj * 8) = make_uint4(lp[0], lp[1], lp[2], lp[3]);
    }
    __syncthreads();
  }
}

// ---------------- prep: codebook -> Ehi/Elo + enorm (exact fp32) --------------
__global__ __launch_bounds__(64) void prep_e(const float* __restrict__ cb,
    u16* __restrict__ Ehi, u16* __restrict__ Elo, float* __restrict__ enorm) {
  int k = blockIdx.x, l = threadIdx.x;
  float nrm = 0.f;
  for (int it = 0; it < 2; ++it) {
    int c = (l + it * 64) * 4;
    float4 v = *(const float4*)(cb + k * 512 + c);
    nrm += v.x * v.x + v.y * v.y + v.z * v.z + v.w * v.w;
    u16 h0 = f2b(v.x), h1 = f2b(v.y), h2 = f2b(v.z), h3 = f2b(v.w);
    uint2 hp; hp.x = (uint32_t)h0 | ((uint32_t)h1 << 16);
    hp.y = (uint32_t)h2 | ((uint32_t)h3 << 16);
    *(uint2*)(Ehi + k * 512 + c) = hp;
    u16 q0 = f2b(v.x - b2f(h0)), q1 = f2b(v.y - b2f(h1));
    u16 q2 = f2b(v.z - b2f(h2)), q3 = f2b(v.w - b2f(h3));
    uint2 lq; lq.x = (uint32_t)q0 | ((uint32_t)q1 << 16);
    lq.y = (uint32_t)q2 | ((uint32_t)q3 << 16);
    *(uint2*)(Elo + k * 512 + c) = lq;
  }
  for (int o = 32; o; o >>= 1) nrm += __shfl_xor(nrm, o);
  if (l == 0) enorm[k] = nrm;
}

// ---------------- prep: Et[c][k] = bf16(codebook[k][c]) (for q GEMM) ----------
__global__ __launch_bounds__(256) void prep_et(const u16* __restrict__ Ehi, u16* __restrict__ Et) {
  __shared__ u16 sm[64][68];
  int k0 = (blockIdx.x & 63) << 6;
  int c0 = (blockIdx.x >> 6) << 6;
  int t = threadIdx.x;
  for (int idx = t; idx < 1024; idx += 256) {
    int ki = idx >> 4, cc = idx & 15;
    uint2 v = *(const uint2*)(Ehi + (k0 + ki) * 512 + c0 + cc * 4);
    *(uint2*)&sm[ki][cc * 4] = v;
  }
  __syncthreads();
  for (int idx = t; idx < 1024; idx += 256) {
    int ci = idx >> 4, kc = idx & 15;
    u16 a0 = sm[kc * 4 + 0][ci], a1 = sm[kc * 4 + 1][ci];
    u16 a2 = sm[kc * 4 + 2][ci], a3 = sm[kc * 4 + 3][ci];
    uint2 o; o.x = (uint32_t)a0 | ((uint32_t)a1 << 16);
    o.y = (uint32_t)a2 | ((uint32_t)a3 << 16);
    *(uint2*)(Et + (c0 + ci) * 4096 + k0 + kc * 4) = o;
  }
}

// ---------------- xnorm[n] = sum_c (hi+lo)^2  (softmax-invariant, fp32-ish) ---
__global__ __launch_bounds__(256) void xnorm_k(const u16* __restrict__ Xhi,
    const u16* __restrict__ Xlo, float* __restrict__ xnorm) {
  int wv = threadIdx.x >> 6, l = threadIdx.x & 63;
  int n = blockIdx.x * 4 + wv;
  float acc = 0.f;
  for (int it = 0; it < 2; ++it) {
    int c = (l + it * 64) * 4;
    uint2 hv = *(const uint2*)(Xhi + n * 512 + c);
    uint2 lv = *(const uint2*)(Xlo + n * 512 + c);
    uint32_t hs[2] = {hv.x, hv.y}, ls[2] = {lv.x, lv.y};
    for (int p = 0; p < 2; ++p) {
      float x0 = b2f((u16)(hs[p] & 0xffff)) + b2f((u16)(ls[p] & 0xffff));
      float x1 = b2f((u16)(hs[p] >> 16)) + b2f((u16)(ls[p] >> 16));
      acc += x0 * x0 + x1 * x1;
    }
  }
  for (int o = 32; o; o >>= 1) acc += __shfl_xor(acc, o);
  if (l == 0) xnorm[n] = acc;
}

// ---------------- GEMM1: D = xnorm + enorm - 2*(Xhi.Ehi + Xlo.Ehi + Xhi.Elo) --
__global__ __launch_bounds__(256) void gemm1(const u16* __restrict__ Xhi,
    const u16* __restrict__ Xlo, const u16* __restrict__ Ehi, const u16* __restrict__ Elo,
    const float* __restrict__ xnorm, const float* __restrict__ enorm, float* __restrict__ D) {
  __shared__ u16 As[2][128 * 32];
  __shared__ u16 Bs[2][128 * 32];
  int bid = blockIdx.x;
  int s = (bid & 7) * 512 + (bid >> 3);      // XCD swizzle (4096 % 8 == 0)
  int rt = s >> 5, ct = s & 31;
  int n0 = rt << 7, k0 = ct << 7;
  int t = threadIdx.x;
  auto stage = [&](int buf, int cc) {
    int phase = cc >> 4;
    const u16* Asrc = (phase == 1) ? Xlo : Xhi;
    const u16* Bsrc = (phase == 2) ? Elo : Ehi;
    int cin = (cc & 15) << 5;
    for (int i = 0; i < 2; ++i) {
      int idx = i * 256 + t;
      int row = idx >> 2, chv = idx & 3;
      g2l16(Asrc + (n0 + row) * 512 + cin + chv * 8, &As[buf][idx * 8]);
      g2l16(Bsrc + (k0 + row) * 512 + cin + chv * 8, &Bs[buf][idx * 8]);
    }
  };
  int l = t & 63, w = t >> 6;
  int wr = (w >> 1) << 6, wc = (w & 1) << 6;
  int lane16 = l & 15, kl = l >> 4;
  f32x4 acc[4][4];
  for (int m = 0; m < 4; ++m)
    for (int nn = 0; nn < 4; ++nn) acc[m][nn] = f32x4{0.f, 0.f, 0.f, 0.f};
  stage(0, 0);
  __syncthreads();
  for (int cc = 0; cc < 48; ++cc) {
    int buf = cc & 1;
    if (cc + 1 < 48) stage(buf ^ 1, cc + 1);
    bf16x8 af[4], bfr[4];
    for (int m = 0; m < 4; ++m)
      af[m] = *(const bf16x8*)&As[buf][(wr + m * 16 + lane16) * 32 + kl * 8];
    for (int nn = 0; nn < 4; ++nn)
      bfr[nn] = *(const bf16x8*)&Bs[buf][(wc + nn * 16 + lane16) * 32 + kl * 8];
    for (int m = 0; m < 4; ++m)
      for (int nn = 0; nn < 4; ++nn)
        acc[m][nn] = __builtin_amdgcn_mfma_f32_16x16x32_bf16(af[m], bfr[nn], acc[m][nn], 0, 0, 0);
    __syncthreads();
  }
  for (int m = 0; m < 4; ++m) {
    for (int r = 0; r < 4; ++r) {
      int row = n0 + wr + m * 16 + kl * 4 + r;
      float xn = xnorm[row];
      for (int nn = 0; nn < 4; ++nn) {
        int col = k0 + wc + nn * 16 + lane16;
        D[row * 4096 + col] = xn + enorm[col] - 2.0f * acc[m][nn][r];
      }
    }
  }
}

// ---------------- row stats: min d, 1/sum exp(m-d), 1/sum exp((m-d)/T) --------
__global__ __launch_bounds__(256) void stats_k(const float* __restrict__ D,
                                               float4* __restrict__ stats) {
  int n = blockIdx.x, t = threadIdx.x;
  const float4* Dr = (const float4*)(D + n * 4096);
  float v[16];
  float mn = 3.4e38f;
  for (int i = 0; i < 4; ++i) {
    float4 x = Dr[t + i * 256];
    v[i * 4 + 0] = x.x; v[i * 4 + 1] = x.y; v[i * 4 + 2] = x.z; v[i * 4 + 3] = x.w;
    mn = fminf(mn, fminf(fminf(x.x, x.y), fminf(x.z, x.w)));
  }
  __shared__ float rmn[4], r1[4], r2[4];
  for (int o = 32; o; o >>= 1) mn = fminf(mn, __shfl_xor(mn, o));
  if ((t & 63) == 0) rmn[t >> 6] = mn;
  __syncthreads();
  mn = fminf(fminf(rmn[0], rmn[1]), fminf(rmn[2], rmn[3]));
  float s1 = 0.f, sT = 0.f;
  for (int i = 0; i < 16; ++i) {
    float d = mn - v[i];
    s1 += __expf(d);
    sT += __expf(d * INVT);
  }
  for (int o = 32; o; o >>= 1) { s1 += __shfl_xor(s1, o); sT += __shfl_xor(sT, o); }
  if ((t & 63) == 0) { r1[t >> 6] = s1; r2[t >> 6] = sT; }
  __syncthreads();
  if (t == 0) {
    s1 = r1[0] + r1[1] + r1[2] + r1[3];
    sT = r2[0] + r2[1] + r2[2] + r2[3];
    stats[n] = make_float4(mn, 1.0f / s1, 1.0f / sT, 0.f);
  }
}

// ------- fused: prob -> assignment (transposed), p -> P bf16 (for q GEMM) -----
__global__ __launch_bounds__(256) void softmax_k(const float* __restrict__ D,
    const float4* __restrict__ stats, float* __restrict__ assign, u16* __restrict__ P) {
  __shared__ float tt[128][33];
  int n0 = blockIdx.x << 5;
  int b = n0 >> 10, hw0 = n0 & 1023;
  int t = threadIdx.x;
  int i = t >> 3, jc = t & 7;
  float4 st = stats[n0 + i];
  float* assignB = assign + b * 4194304 + hw0;
  const float* Dr = D + (n0 + i) * 4096;
  u16* Pr = P + (n0 + i) * 4096;
  for (int kt = 0; kt < 32; ++kt) {
    int kb = kt << 7;
    for (int it = 0; it < 4; ++it) {
      int col4 = (jc + it * 8) * 4;
      float4 dv = *(const float4*)(Dr + kb + col4);
      float e0 = st.x - dv.x, e1 = st.x - dv.y, e2 = st.x - dv.z, e3 = st.x - dv.w;
      // p = softmax(-d) in bf16 for the q GEMM
      u16 p0 = f2b(__expf(e0) * st.y), p1 = f2b(__expf(e1) * st.y);
      u16 p2 = f2b(__expf(e2) * st.y), p3 = f2b(__expf(e3) * st.y);
      uint2 pp; pp.x = (uint32_t)p0 | ((uint32_t)p1 << 16);
      pp.y = (uint32_t)p2 | ((uint32_t)p3 << 16);
      *(uint2*)(Pr + kb + col4) = pp;
      // prob = softmax(-d/T) -> LDS transpose tile
      tt[col4 + 0][i] = __expf(e0 * INVT) * st.z;
      tt[col4 + 1][i] = __expf(e1 * INVT) * st.z;
      tt[col4 + 2][i] = __expf(e2 * INVT) * st.z;
      tt[col4 + 3][i] = __expf(e3 * INVT) * st.z;
    }
    __syncthreads();
    for (int idx = t; idx < 1024; idx += 256) {
      int j = idx >> 3, ic = idx & 7;
      float4 o;
      o.x = tt[j][ic * 4 + 0]; o.y = tt[j][ic * 4 + 1];
      o.z = tt[j][ic * 4 + 2]; o.w = tt[j][ic * 4 + 3];
      *(float4*)(assignB + (kb + j) * 1024 + ic * 4) = o;
    }
    __syncthreads();
  }
}

// ---------------- GEMM2: q^T = Et (c x K) . P^T  -> (b, c, hw) directly -------
__global__ __launch_bounds__(256) void gemm2(const u16* __restrict__ Et,
    const u16* __restrict__ P, float* __restrict__ Q) {
  __shared__ u16 As[2][128 * 32];
  __shared__ u16 Bs[2][128 * 32];
  int bid = blockIdx.x;
  int s = (bid & 7) * 64 + (bid >> 3);       // XCD swizzle (512 % 8 == 0)
  int rt = s >> 7, ct = s & 127;
  int c0 = rt << 7, n0 = ct << 7;
  int t = threadIdx.x;
  auto stage = [&](int buf, int cc) {
    int cin = cc << 5;
    for (int i = 0; i < 2; ++i) {
      int idx = i * 256 + t;
      int row = idx >> 2, chv = idx & 3;
      g2l16(Et + (c0 + row) * 4096 + cin + chv * 8, &As[buf][idx * 8]);
      g2l16(P + (n0 + row) * 4096 + cin + chv * 8, &Bs[buf][idx * 8]);
    }
  };
  int l = t & 63, w = t >> 6;
  int wr = (w >> 1) << 6, wc = (w & 1) << 6;
  int lane16 = l & 15, kl = l >> 4;
  f32x4 acc[4][4];
  for (int m = 0; m < 4; ++m)
    for (int nn = 0; nn < 4; ++nn) acc[m][nn] = f32x4{0.f, 0.f, 0.f, 0.f};
  stage(0, 0);
  __syncthreads();
  for (int cc = 0; cc < 128; ++cc) {
    int buf = cc & 1;
    if (cc + 1 < 128) stage(buf ^ 1, cc + 1);
    bf16x8 af[4], bfr[4];
    for (int m = 0; m < 4; ++m)
      af[m] = *(const bf16x8*)&As[buf][(wr + m * 16 + lane16) * 32 + kl * 8];
    for (int nn = 0; nn < 4; ++nn)
      bfr[nn] = *(const bf16x8*)&Bs[buf][(wc + nn * 16 + lane16) * 32 + kl * 8];
    for (int m = 0; m < 4; ++m)
      for (int nn = 0; nn < 4; ++nn)
        acc[m][nn] = __builtin_amdgcn_mfma_f32_16x16x32_bf16(af[m], bfr[nn], acc[m][nn], 0, 0, 0);
    __syncthreads();
  }
  for (int m = 0; m < 4; ++m) {
    for (int r = 0; r < 4; ++r) {
      int crow = c0 + wr + m * 16 + kl * 4 + r;
      for (int nn = 0; nn < 4; ++nn) {
        int col = n0 + wc + nn * 16 + lane16;
        int bb = col >> 10, hw = col & 1023;
        Q[bb * 524288 + crow * 1024 + hw] = acc[m][nn][r];
      }
    }
  }
}

extern "C" void kernel_launch(void* const* d_in, const int* in_sizes, int n_in,
                              void* d_out, int out_size, void* d_ws, size_t ws_size,
                              hipStream_t stream) {
  const float* feat = (const float*)d_in[0];   // (16, 512, 32, 32)
  const float* cb = (const float*)d_in[1];     // (4096, 512)
  float* out = (float*)d_out;
  float* q_out = out;                          // 8388608
  float* a_out = out + 8388608;                // 67108864
  float* d_dist = out + 75497472;              // 67108864

  char* ws = (char*)d_ws;
  u16* Xhi = (u16*)(ws + 0);
  u16* Xlo = (u16*)(ws + 16777216);
  u16* Ehi = (u16*)(ws + 33554432);
  u16* Elo = (u16*)(ws + 37748736);
  u16* Et  = (u16*)(ws + 41943040);
  float* xnorm = (float*)(ws + 46137344);
  float* enorm = (float*)(ws + 46202880);
  float4* stats = (float4*)(ws + 46219264);
  u16* P = (u16*)(ws + 46481408);              // ends at ~180.7 MB

  prep_x<<<256, 256, 0, stream>>>(feat, Xhi, Xlo);
  prep_e<<<4096, 64, 0, stream>>>(cb, Ehi, Elo, enorm);
  prep_et<<<512, 256, 0, stream>>>(Ehi, Et);
  xnorm_k<<<4096, 256, 0, stream>>>(Xhi, Xlo, xnorm);
  gemm1<<<4096, 256, 0, stream>>>(Xhi, Xlo, Ehi, Elo, xnorm, enorm, d_dist);
  stats_k<<<16384, 256, 0, stream>>>(d_dist, stats);
  softmax_k<<<512, 256, 0, stream>>>(d_dist, stats, a_out, P);
  gemm2<<<512, 256, 0, stream>>>(Et, P, q_out);
}

// Round 2
// 551.071 us; speedup vs baseline: 1.1282x; 1.1282x over previous
//
#include <hip/hip_runtime.h>
#include <hip/hip_bf16.h>
#include <stdint.h>

typedef unsigned short u16;
typedef __bf16 bf16x8 __attribute__((ext_vector_type(8)));
typedef float f32x4 __attribute__((ext_vector_type(4)));

#define INVT 14.2857142857142857f  // 1/0.07

__device__ __forceinline__ u16 f2b(float f) {
  __hip_bfloat16 h = __float2bfloat16(f);
  return __builtin_bit_cast(u16, h);
}
__device__ __forceinline__ float b2f(u16 u) {
  union { uint32_t i; float f; } z; z.i = ((uint32_t)u) << 16; return z.f;
}
__device__ __forceinline__ void g2l16(const void* g, void* l) {
  __builtin_amdgcn_global_load_lds(
      (__attribute__((address_space(1))) void*)(uintptr_t)g,
      (__attribute__((address_space(3))) void*)(uint32_t)(uintptr_t)l, 16, 0, 0);
}

// ---------------- prep: feat (b,c,hw) -> Xhi/Xlo bf16 (n, c), n = b*1024+hw ----
__global__ __launch_bounds__(256) void prep_x(const float* __restrict__ feat,
                                              u16* __restrict__ Xhi, u16* __restrict__ Xlo) {
  __shared__ float sm[64][65];
  int b = blockIdx.x >> 4;
  int hw0 = (blockIdx.x & 15) << 6;
  int t = threadIdx.x;
  int hwi = t & 63, ci0 = t >> 6;
  for (int c0 = 0; c0 < 512; c0 += 64) {
    for (int ci = ci0; ci < 64; ci += 4)
      sm[ci][hwi] = feat[((b * 512 + c0 + ci) << 10) + hw0 + hwi];
    __syncthreads();
    int cj = t & 7;
    for (int w = 0; w < 2; ++w) {
      int hj = (t >> 3) + (w << 5);
      int n = (b << 10) + hw0 + hj;
      uint32_t hp[4], lp[4];
      for (int p = 0; p < 4; ++p) {
        float v0 = sm[cj * 8 + p * 2 + 0][hj];
        float v1 = sm[cj * 8 + p * 2 + 1][hj];
        u16 h0 = f2b(v0), h1 = f2b(v1);
        u16 l0 = f2b(v0 - b2f(h0)), l1 = f2b(v1 - b2f(h1));
        hp[p] = (uint32_t)h0 | ((uint32_t)h1 << 16);
        lp[p] = (uint32_t)l0 | ((uint32_t)l1 << 16);
      }
      *(uint4*)(Xhi + n * 512 + c0 + cj * 8) = make_uint4(hp[0], hp[1], hp[2], hp[3]);
      *(uint4*)(Xlo + n * 512 + c0 + cj * 8) = make_uint4(lp[0], lp[1], lp[2], lp[3]);
    }
    __syncthreads();
  }
}

// ---------------- prep: codebook -> Ehi/Elo + enorm (exact fp32) --------------
__global__ __launch_bounds__(64) void prep_e(const float* __restrict__ cb,
    u16* __restrict__ Ehi, u16* __restrict__ Elo, float* __restrict__ enorm) {
  int k = blockIdx.x, l = threadIdx.x;
  float nrm = 0.f;
  for (int it = 0; it < 2; ++it) {
    int c = (l + it * 64) * 4;
    float4 v = *(const float4*)(cb + k * 512 + c);
    nrm += v.x * v.x + v.y * v.y + v.z * v.z + v.w * v.w;
    u16 h0 = f2b(v.x), h1 = f2b(v.y), h2 = f2b(v.z), h3 = f2b(v.w);
    uint2 hp; hp.x = (uint32_t)h0 | ((uint32_t)h1 << 16);
    hp.y = (uint32_t)h2 | ((uint32_t)h3 << 16);
    *(uint2*)(Ehi + k * 512 + c) = hp;
    u16 q0 = f2b(v.x - b2f(h0)), q1 = f2b(v.y - b2f(h1));
    u16 q2 = f2b(v.z - b2f(h2)), q3 = f2b(v.w - b2f(h3));
    uint2 lq; lq.x = (uint32_t)q0 | ((uint32_t)q1 << 16);
    lq.y = (uint32_t)q2 | ((uint32_t)q3 << 16);
    *(uint2*)(Elo + k * 512 + c) = lq;
  }
  for (int o = 32; o; o >>= 1) nrm += __shfl_xor(nrm, o);
  if (l == 0) enorm[k] = nrm;
}

// ---------------- prep: Et[c][k] = bf16(codebook[k][c]) (for q GEMM) ----------
__global__ __launch_bounds__(256) void prep_et(const u16* __restrict__ Ehi, u16* __restrict__ Et) {
  __shared__ u16 sm[64][68];
  int k0 = (blockIdx.x & 63) << 6;
  int c0 = (blockIdx.x >> 6) << 6;
  int t = threadIdx.x;
  for (int idx = t; idx < 1024; idx += 256) {
    int ki = idx >> 4, cc = idx & 15;
    uint2 v = *(const uint2*)(Ehi + (k0 + ki) * 512 + c0 + cc * 4);
    *(uint2*)&sm[ki][cc * 4] = v;
  }
  __syncthreads();
  for (int idx = t; idx < 1024; idx += 256) {
    int ci = idx >> 4, kc = idx & 15;
    u16 a0 = sm[kc * 4 + 0][ci], a1 = sm[kc * 4 + 1][ci];
    u16 a2 = sm[kc * 4 + 2][ci], a3 = sm[kc * 4 + 3][ci];
    uint2 o; o.x = (uint32_t)a0 | ((uint32_t)a1 << 16);
    o.y = (uint32_t)a2 | ((uint32_t)a3 << 16);
    *(uint2*)(Et + (c0 + ci) * 4096 + k0 + kc * 4) = o;
  }
}

// ---------------- xnorm[n] = sum_c (hi+lo)^2  (softmax-invariant) -------------
__global__ __launch_bounds__(256) void xnorm_k(const u16* __restrict__ Xhi,
    const u16* __restrict__ Xlo, float* __restrict__ xnorm) {
  int wv = threadIdx.x >> 6, l = threadIdx.x & 63;
  int n = blockIdx.x * 4 + wv;
  float acc = 0.f;
  for (int it = 0; it < 2; ++it) {
    int c = (l + it * 64) * 4;
    uint2 hv = *(const uint2*)(Xhi + n * 512 + c);
    uint2 lv = *(const uint2*)(Xlo + n * 512 + c);
    uint32_t hs[2] = {hv.x, hv.y}, ls[2] = {lv.x, lv.y};
    for (int p = 0; p < 2; ++p) {
      float x0 = b2f((u16)(hs[p] & 0xffff)) + b2f((u16)(ls[p] & 0xffff));
      float x1 = b2f((u16)(hs[p] >> 16)) + b2f((u16)(ls[p] >> 16));
      acc += x0 * x0 + x1 * x1;
    }
  }
  for (int o = 32; o; o >>= 1) acc += __shfl_xor(acc, o);
  if (l == 0) xnorm[n] = acc;
}

// ================= GEMM1: 256x256 tile, BK=64, 8 waves, 8-phase ===============
// D = xnorm + enorm - 2*(Xhi.Ehi + Xlo.Ehi + Xhi.Elo), Keff = 1536 = 24 Ktiles.
// LDS halves by read-retirement: A-half h = rows {h*64..+64} U {128+h*64..+64}
// (wave wm reads only rows wm*128+..; m-frags 0-3 in phases q0/q1, 4-7 in q2/q3).
// B-half hb = rows with bit5==hb (n-frags 0-1 vs 2-3 across all 4 waves-n).
// Swizzle: LDS chunk (row, c8) holds global col-chunk (c8 ^ (row&7)) [involution].

__device__ __forceinline__ void stageA_g1(const u16* __restrict__ g, u16* l, int h, int t) {
  int r0 = t >> 3, c = ((t & 7) ^ (r0 & 7)) * 8, cw = (t & 7) * 8;
  int ra = h * 64 + r0, rb = 128 + h * 64 + r0;
  g2l16(g + ra * 512 + c, l + ra * 64 + cw);
  g2l16(g + rb * 512 + c, l + rb * 64 + cw);
}
__device__ __forceinline__ void stageB_g1(const u16* __restrict__ g, u16* l, int hb, int t) {
  int r0 = t >> 3, c = ((t & 7) ^ (r0 & 7)) * 8, cw = (t & 7) * 8;
  int ra = (r0 >> 5) * 64 + hb * 32 + (r0 & 31);
  int rb = ((r0 + 64) >> 5) * 64 + hb * 32 + (r0 & 31);
  g2l16(g + ra * 512 + c, l + ra * 64 + cw);
  g2l16(g + rb * 512 + c, l + rb * 64 + cw);
}

template<int Q>
__device__ __forceinline__ void phase_ld(const u16* Ab, const u16* Bb,
    int wm, int wn, int lane16, int kl, bf16x8 (&af)[4][2], bf16x8 (&bf2)[2][2]) {
  int sw = lane16 & 7;
  if constexpr (Q == 0 || Q == 2) {
#pragma unroll
    for (int m = 0; m < 4; ++m)
#pragma unroll
      for (int s = 0; s < 2; ++s)
        af[m][s] = *(const bf16x8*)(Ab + (wm * 128 + ((Q >> 1) * 4 + m) * 16 + lane16) * 64
                                    + (((s * 4 + kl) ^ sw) * 8));
  }
  if constexpr (Q != 2) {
    constexpr int NF0 = (Q == 1) ? 2 : 0;
#pragma unroll
    for (int n = 0; n < 2; ++n)
#pragma unroll
      for (int s = 0; s < 2; ++s)
        bf2[n][s] = *(const bf16x8*)(Bb + (wn * 64 + (NF0 + n) * 16 + lane16) * 64
                                     + (((s * 4 + kl) ^ sw) * 8));
  }
}
template<int Q>
__device__ __forceinline__ void phase_mm(bf16x8 (&af)[4][2], bf16x8 (&bf2)[2][2],
                                         f32x4 (&acc)[8][4]) {
  constexpr int MQ = (Q >> 1) * 4;
  constexpr int NF0 = (Q == 1 || Q == 2) ? 2 : 0;
#pragma unroll
  for (int m = 0; m < 4; ++m)
#pragma unroll
    for (int n = 0; n < 2; ++n)
#pragma unroll
      for (int s = 0; s < 2; ++s)
        acc[MQ + m][NF0 + n] = __builtin_amdgcn_mfma_f32_16x16x32_bf16(
            af[m][s], bf2[n][s], acc[MQ + m][NF0 + n], 0, 0, 0);
}

#define FENCE() asm volatile("" ::: "memory")
#define BAR() __builtin_amdgcn_s_barrier()
#define VMW4() asm volatile("s_waitcnt vmcnt(4)" ::: "memory")
#define VMW0() asm volatile("s_waitcnt vmcnt(0)" ::: "memory")

__global__ __launch_bounds__(512, 2) void gemm1_8ph(const u16* __restrict__ Xhi,
    const u16* __restrict__ Xlo, const u16* __restrict__ Ehi, const u16* __restrict__ Elo,
    const float* __restrict__ xnorm, const float* __restrict__ enorm, float* __restrict__ D) {
  __shared__ __align__(16) u16 lds[2][2][256 * 64];  // [buf][A/B][row*64+col] = 128 KB
  int bid = blockIdx.x;
  int s = (bid & 7) * 128 + (bid >> 3);   // XCD swizzle, 1024 % 8 == 0 -> bijective
  int rt = s >> 4, ct = s & 15;
  int n0 = rt << 8, k0 = ct << 8;
  int t = threadIdx.x;
  int l = t & 63, w = t >> 6;
  int wm = w >> 2, wn = w & 3;
  int lane16 = l & 15, kl = l >> 4;

  u16* lA0 = &lds[0][0][0]; u16* lB0 = &lds[0][1][0];
  u16* lA1 = &lds[1][0][0]; u16* lB1 = &lds[1][1][0];

  auto gA = [&](int kt) { return ((kt >> 3) == 1 ? Xlo : Xhi) + n0 * 512 + (kt & 7) * 64; };
  auto gB = [&](int kt) { return ((kt >> 3) == 2 ? Elo : Ehi) + k0 * 512 + (kt & 7) * 64; };

  f32x4 acc[8][4];
#pragma unroll
  for (int m = 0; m < 8; ++m)
#pragma unroll
    for (int n = 0; n < 4; ++n) acc[m][n] = f32x4{0.f, 0.f, 0.f, 0.f};
  bf16x8 af[4][2], bf2[2][2];

  // prologue: pair 0 (Ktiles 0,1): b0 all four halves + b1.Aa + b1.Bb
  stageA_g1(gA(0), lA0, 0, t);
  stageB_g1(gB(0), lB0, 1, t);
  stageB_g1(gB(0), lB0, 0, t);
  stageA_g1(gA(0), lA0, 1, t);
  stageA_g1(gA(1), lA1, 0, t);
  stageB_g1(gB(1), lB1, 1, t);
  VMW4();  // b0 fully landed; b1.Aa/b1.Bb may remain in flight (covered at ph3-end)
  BAR();

#pragma unroll 1
  for (int i = 0; i < 12; ++i) {
    int ktO = 2 * i + 1;              // this pair's odd Ktile (-> buf1)
    int ktE2 = 2 * i + 2, ktO2 = 2 * i + 3;  // next pair
    bool more = (i < 11);
    // ---- ph0: buf0 q0 ---- stage b1.Ba (this pair)
    phase_ld<0>(lA0, lB0, wm, wn, lane16, kl, af, bf2);
    stageB_g1(gB(ktO), lB1, 0, t);
    FENCE(); BAR();
    __builtin_amdgcn_s_setprio(1); phase_mm<0>(af, bf2, acc); __builtin_amdgcn_s_setprio(0);
    FENCE(); BAR();
    // ---- ph1: buf0 q1 ---- stage b1.Ab (this pair)
    phase_ld<1>(lA0, lB0, wm, wn, lane16, kl, af, bf2);
    stageA_g1(gA(ktO), lA1, 1, t);
    FENCE(); BAR();
    __builtin_amdgcn_s_setprio(1); phase_mm<1>(af, bf2, acc); __builtin_amdgcn_s_setprio(0);
    FENCE(); BAR();
    // ---- ph2: buf0 q2 ---- stage b0.Aa (next pair)
    phase_ld<2>(lA0, lB0, wm, wn, lane16, kl, af, bf2);
    if (more) stageA_g1(gA(ktE2), lA0, 0, t);
    FENCE(); BAR();
    __builtin_amdgcn_s_setprio(1); phase_mm<2>(af, bf2, acc); __builtin_amdgcn_s_setprio(0);
    FENCE(); BAR();
    // ---- ph3: buf0 q3 ---- stage b0.Bb (next pair); W2 wait for buf1
    phase_ld<3>(lA0, lB0, wm, wn, lane16, kl, af, bf2);
    if (more) stageB_g1(gB(ktE2), lB0, 1, t);
    FENCE(); BAR();
    __builtin_amdgcn_s_setprio(1); phase_mm<3>(af, bf2, acc); __builtin_amdgcn_s_setprio(0);
    if (i == 11) { VMW0(); } else { VMW4(); }
    BAR();
    // ---- ph4: buf1 q0 ---- stage b0.Ba (next pair)
    phase_ld<0>(lA1, lB1, wm, wn, lane16, kl, af, bf2);
    if (more) stageB_g1(gB(ktE2), lB0, 0, t);
    FENCE(); BAR();
    __builtin_amdgcn_s_setprio(1); phase_mm<0>(af, bf2, acc); __builtin_amdgcn_s_setprio(0);
    FENCE(); BAR();
    // ---- ph5: buf1 q1 ---- stage b0.Ab (next pair)
    phase_ld<1>(lA1, lB1, wm, wn, lane16, kl, af, bf2);
    if (more) stageA_g1(gA(ktE2), lA0, 1, t);
    FENCE(); BAR();
    __builtin_amdgcn_s_setprio(1); phase_mm<1>(af, bf2, acc); __builtin_amdgcn_s_setprio(0);
    FENCE(); BAR();
    // ---- ph6: buf1 q2 ---- stage b1.Aa (next pair)
    phase_ld<2>(lA1, lB1, wm, wn, lane16, kl, af, bf2);
    if (more) stageA_g1(gA(ktO2), lA1, 0, t);
    FENCE(); BAR();
    __builtin_amdgcn_s_setprio(1); phase_mm<2>(af, bf2, acc); __builtin_amdgcn_s_setprio(0);
    FENCE(); BAR();
    // ---- ph7: buf1 q3 ---- stage b1.Bb (next pair); W1 wait for buf0
    phase_ld<3>(lA1, lB1, wm, wn, lane16, kl, af, bf2);
    if (more) stageB_g1(gB(ktO2), lB1, 1, t);
    FENCE(); BAR();
    __builtin_amdgcn_s_setprio(1); phase_mm<3>(af, bf2, acc); __builtin_amdgcn_s_setprio(0);
    if (more) { VMW4(); }
    BAR();
  }

  // epilogue: D = xn + en - 2*acc
  float en[4];
#pragma unroll
  for (int nf = 0; nf < 4; ++nf) en[nf] = enorm[k0 + wn * 64 + nf * 16 + lane16];
#pragma unroll
  for (int mf = 0; mf < 8; ++mf) {
#pragma unroll
    for (int r = 0; r < 4; ++r) {
      int row = n0 + wm * 128 + mf * 16 + kl * 4 + r;
      float xv = xnorm[row];
      float* Drow = D + (size_t)row * 4096 + k0 + wn * 64 + lane16;
#pragma unroll
      for (int nf = 0; nf < 4; ++nf)
        Drow[nf * 16] = xv + en[nf] - 2.0f * acc[mf][nf][r];
    }
  }
}

// ---------------- row stats: min d, 1/sum exp(m-d), 1/sum exp((m-d)/T) --------
__global__ __launch_bounds__(256) void stats_k(const float* __restrict__ D,
                                               float4* __restrict__ stats) {
  int n = blockIdx.x, t = threadIdx.x;
  const float4* Dr = (const float4*)(D + n * 4096);
  float v[16];
  float mn = 3.4e38f;
  for (int i = 0; i < 4; ++i) {
    float4 x = Dr[t + i * 256];
    v[i * 4 + 0] = x.x; v[i * 4 + 1] = x.y; v[i * 4 + 2] = x.z; v[i * 4 + 3] = x.w;
    mn = fminf(mn, fminf(fminf(x.x, x.y), fminf(x.z, x.w)));
  }
  __shared__ float rmn[4], r1[4], r2[4];
  for (int o = 32; o; o >>= 1) mn = fminf(mn, __shfl_xor(mn, o));
  if ((t & 63) == 0) rmn[t >> 6] = mn;
  __syncthreads();
  mn = fminf(fminf(rmn[0], rmn[1]), fminf(rmn[2], rmn[3]));
  float s1 = 0.f, sT = 0.f;
  for (int i = 0; i < 16; ++i) {
    float d = mn - v[i];
    s1 += __expf(d);
    sT += __expf(d * INVT);
  }
  for (int o = 32; o; o >>= 1) { s1 += __shfl_xor(s1, o); sT += __shfl_xor(sT, o); }
  if ((t & 63) == 0) { r1[t >> 6] = s1; r2[t >> 6] = sT; }
  __syncthreads();
  if (t == 0) {
    s1 = r1[0] + r1[1] + r1[2] + r1[3];
    sT = r2[0] + r2[1] + r2[2] + r2[3];
    stats[n] = make_float4(mn, 1.0f / s1, 1.0f / sT, 0.f);
  }
}

// ------- fused: prob -> assignment (transposed), p -> P bf16 (for q GEMM) -----
__global__ __launch_bounds__(256) void softmax_k(const float* __restrict__ D,
    const float4* __restrict__ stats, float* __restrict__ assign, u16* __restrict__ P) {
  __shared__ float tt[128][33];
  int n0 = blockIdx.x << 5;
  int b = n0 >> 10, hw0 = n0 & 1023;
  int t = threadIdx.x;
  int i = t >> 3, jc = t & 7;
  float4 st = stats[n0 + i];
  float* assignB = assign + b * 4194304 + hw0;
  const float* Dr = D + (n0 + i) * 4096;
  u16* Pr = P + (n0 + i) * 4096;
  for (int kt = 0; kt < 32; ++kt) {
    int kb = kt << 7;
    for (int it = 0; it < 4; ++it) {
      int col4 = (jc + it * 8) * 4;
      float4 dv = *(const float4*)(Dr + kb + col4);
      float e0 = st.x - dv.x, e1 = st.x - dv.y, e2 = st.x - dv.z, e3 = st.x - dv.w;
      u16 p0 = f2b(__expf(e0) * st.y), p1 = f2b(__expf(e1) * st.y);
      u16 p2 = f2b(__expf(e2) * st.y), p3 = f2b(__expf(e3) * st.y);
      uint2 pp; pp.x = (uint32_t)p0 | ((uint32_t)p1 << 16);
      pp.y = (uint32_t)p2 | ((uint32_t)p3 << 16);
      *(uint2*)(Pr + kb + col4) = pp;
      tt[col4 + 0][i] = __expf(e0 * INVT) * st.z;
      tt[col4 + 1][i] = __expf(e1 * INVT) * st.z;
      tt[col4 + 2][i] = __expf(e2 * INVT) * st.z;
      tt[col4 + 3][i] = __expf(e3 * INVT) * st.z;
    }
    __syncthreads();
    for (int idx = t; idx < 1024; idx += 256) {
      int j = idx >> 3, ic = idx & 7;
      float4 o;
      o.x = tt[j][ic * 4 + 0]; o.y = tt[j][ic * 4 + 1];
      o.z = tt[j][ic * 4 + 2]; o.w = tt[j][ic * 4 + 3];
      *(float4*)(assignB + (kb + j) * 1024 + ic * 4) = o;
    }
    __syncthreads();
  }
}

// ---------------- GEMM2: q^T = Et (c x K) . P^T  -> (b, c, hw) directly -------
__global__ __launch_bounds__(256) void gemm2(const u16* __restrict__ Et,
    const u16* __restrict__ P, float* __restrict__ Q) {
  __shared__ u16 As[2][128 * 32];
  __shared__ u16 Bs[2][128 * 32];
  int bid = blockIdx.x;
  int s = (bid & 7) * 64 + (bid >> 3);
  int rt = s >> 7, ct = s & 127;
  int c0 = rt << 7, n0 = ct << 7;
  int t = threadIdx.x;
  auto stage = [&](int buf, int cc) {
    int cin = cc << 5;
    for (int i = 0; i < 2; ++i) {
      int idx = i * 256 + t;
      int row = idx >> 2, chv = idx & 3;
      g2l16(Et + (c0 + row) * 4096 + cin + chv * 8, &As[buf][idx * 8]);
      g2l16(P + (n0 + row) * 4096 + cin + chv * 8, &Bs[buf][idx * 8]);
    }
  };
  int l = t & 63, w = t >> 6;
  int wr = (w >> 1) << 6, wc = (w & 1) << 6;
  int lane16 = l & 15, kl = l >> 4;
  f32x4 acc[4][4];
  for (int m = 0; m < 4; ++m)
    for (int nn = 0; nn < 4; ++nn) acc[m][nn] = f32x4{0.f, 0.f, 0.f, 0.f};
  stage(0, 0);
  __syncthreads();
  for (int cc = 0; cc < 128; ++cc) {
    int buf = cc & 1;
    if (cc + 1 < 128) stage(buf ^ 1, cc + 1);
    bf16x8 af[4], bfr[4];
    for (int m = 0; m < 4; ++m)
      af[m] = *(const bf16x8*)&As[buf][(wr + m * 16 + lane16) * 32 + kl * 8];
    for (int nn = 0; nn < 4; ++nn)
      bfr[nn] = *(const bf16x8*)&Bs[buf][(wc + nn * 16 + lane16) * 32 + kl * 8];
    for (int m = 0; m < 4; ++m)
      for (int nn = 0; nn < 4; ++nn)
        acc[m][nn] = __builtin_amdgcn_mfma_f32_16x16x32_bf16(af[m], bfr[nn], acc[m][nn], 0, 0, 0);
    __syncthreads();
  }
  for (int m = 0; m < 4; ++m) {
    for (int r = 0; r < 4; ++r) {
      int crow = c0 + wr + m * 16 + kl * 4 + r;
      for (int nn = 0; nn < 4; ++nn) {
        int col = n0 + wc + nn * 16 + lane16;
        int bb = col >> 10, hw = col & 1023;
        Q[bb * 524288 + crow * 1024 + hw] = acc[m][nn][r];
      }
    }
  }
}

extern "C" void kernel_launch(void* const* d_in, const int* in_sizes, int n_in,
                              void* d_out, int out_size, void* d_ws, size_t ws_size,
                              hipStream_t stream) {
  const float* feat = (const float*)d_in[0];   // (16, 512, 32, 32)
  const float* cb = (const float*)d_in[1];     // (4096, 512)
  float* out = (float*)d_out;
  float* q_out = out;                          // 8388608
  float* a_out = out + 8388608;                // 67108864
  float* d_dist = out + 75497472;              // 67108864

  char* ws = (char*)d_ws;
  u16* Xhi = (u16*)(ws + 0);
  u16* Xlo = (u16*)(ws + 16777216);
  u16* Ehi = (u16*)(ws + 33554432);
  u16* Elo = (u16*)(ws + 37748736);
  u16* Et  = (u16*)(ws + 41943040);
  float* xnorm = (float*)(ws + 46137344);
  float* enorm = (float*)(ws + 46202880);
  float4* stats = (float4*)(ws + 46219264);
  u16* P = (u16*)(ws + 46481408);              // ends at ~180.7 MB

  prep_x<<<256, 256, 0, stream>>>(feat, Xhi, Xlo);
  prep_e<<<4096, 64, 0, stream>>>(cb, Ehi, Elo, enorm);
  prep_et<<<512, 256, 0, stream>>>(Ehi, Et);
  xnorm_k<<<4096, 256, 0, stream>>>(Xhi, Xlo, xnorm);
  gemm1_8ph<<<1024, 512, 0, stream>>>(Xhi, Xlo, Ehi, Elo, xnorm, enorm, d_dist);
  stats_k<<<16384, 256, 0, stream>>>(d_dist, stats);
  softmax_k<<<512, 256, 0, stream>>>(d_dist, stats, a_out, P);
  gemm2<<<512, 256, 0, stream>>>(Et, P, q_out);
}